// Round 4
// baseline (514.816 us; speedup 1.0000x reference)
//
#include <hip/hip_runtime.h>

typedef unsigned short u16;
typedef __attribute__((ext_vector_type(8))) short bf16x8;
typedef __attribute__((ext_vector_type(4))) float f32x4;

constexpr int DM = 1024;   // d_model
constexpr int NH = 16;     // n_head
constexpr int DH = 64;     // d_head
constexpr int QL = 1024;   // qlen
constexpr int ML = 512;    // mlen
constexpr int KL = 1536;   // klen = qlen + mlen
constexpr int RL = 2560;   // rlen = qlen + klen
constexpr int BS = 4;      // batch
constexpr int JT = KL / 64;  // 24 j-tiles of 64
constexpr float SCALE = 0.125f;  // 1/sqrt(64)
constexpr float SC2 = 0.125f * 1.4426950408889634f;  // SCALE * log2(e)

static __device__ __forceinline__ u16 f2bf(float f) {
    unsigned u = __float_as_uint(f);
    u += 0x7fffu + ((u >> 16) & 1u);   // RNE
    return (u16)(u >> 16);
}

// async global->LDS DMA, 16B per lane. LDS dest = wave-uniform base + lane*16.
// Global source address is PER-LANE (gather allowed).
static __device__ __forceinline__ void glds16(const u16* g, u16* l) {
    __builtin_amdgcn_global_load_lds(
        (const __attribute__((address_space(1))) unsigned int*)g,
        (__attribute__((address_space(3))) unsigned int*)l,
        16, 0, 0);
}

// ---------------------------------------------------------------------------
// Fused prep (1 launch): blocks [0,17408) fp32->bf16 convert of cat/r/Wo;
// [17408,18432) W transpose-convert; [18432,43008) mask/seg bit-pack.
// pk layout: [b][itile][jt][row0..63] (coalesced 1KB per (itile,jt) gather).
// ---------------------------------------------------------------------------
__global__ __launch_bounds__(256) void prep_kernel(
    const float* __restrict__ mems, const float* __restrict__ h,
    const float* __restrict__ r, const float* __restrict__ Wo,
    const float* __restrict__ mask, const float* __restrict__ segm,
    const float* __restrict__ Wq, const float* __restrict__ Wk,
    const float* __restrict__ Wv, const float* __restrict__ Wr,
    u16* __restrict__ catb, u16* __restrict__ rb, u16* __restrict__ wob,
    u16* __restrict__ WqT, u16* __restrict__ WkT,
    u16* __restrict__ WvT, u16* __restrict__ WrT,
    ulonglong2* __restrict__ pk)
{
    __shared__ float smem[64 * 65];
    const int id = blockIdx.x;
    const int t = threadIdx.x;

    if (id < 17408) {        // ---- convert ----
        const long C0 = (long)ML * BS * DM;
        const long C1 = (long)KL * BS * DM;
        const long C2 = C1 + (long)RL * BS * DM;
        long g = ((long)id * 256 + t) * 4;
        const float* src; u16* dst;
        if (g < C0)      { src = mems + g;        dst = catb + g; }
        else if (g < C1) { src = h + (g - C0);    dst = catb + g; }
        else if (g < C2) { src = r + (g - C1);    dst = rb + (g - C1); }
        else             { src = Wo + (g - C2);   dst = wob + (g - C2); }
        float4 v = *(const float4*)src;
        unsigned lo = (unsigned)f2bf(v.x) | ((unsigned)f2bf(v.y) << 16);
        unsigned hi = (unsigned)f2bf(v.z) | ((unsigned)f2bf(v.w) << 16);
        *(uint2*)dst = make_uint2(lo, hi);
        return;
    }
    if (id < 18432) {        // ---- W transpose ----
        float (*tile)[65] = (float(*)[65])smem;
        const int local = id - 17408;
        const float* W; u16* WT;
        switch (local >> 8) {
            case 0:  W = Wq; WT = WqT; break;
            case 1:  W = Wk; WT = WkT; break;
            case 2:  W = Wv; WT = WvT; break;
            default: W = Wr; WT = WrT; break;
        }
        const int k0 = (local & 15) * 64, n0 = ((local >> 4) & 15) * 64;
        const int tr = t >> 6, tc = t & 63;
        #pragma unroll
        for (int rr = 0; rr < 16; rr++) {
            int rw = tr + rr * 4;
            tile[rw][tc] = W[(size_t)(k0 + rw) * DM + n0 + tc];
        }
        __syncthreads();
        #pragma unroll
        for (int rr = 0; rr < 16; rr++) {
            int n = tr + rr * 4;
            WT[(size_t)(n0 + n) * DM + k0 + tc] = f2bf(tile[tc][n]);
        }
        return;
    }
    // ---- pack mask/seg bits ----
    {
        float* mk = smem;
        float* sg = smem + 256;
        const int local = id - 18432;
        const int i = local / JT, jt = local - i * JT;
        const size_t base = ((size_t)i * KL + jt * 64) * BS;   // float idx (j*4+b)
        mk[t] = mask[base + t];
        float2 s2 = ((const float2*)(segm + base * 2))[t];
        sg[t] = s2.y;
        __syncthreads();
        const int b = t >> 6, lane = t & 63;
        const unsigned long long mb = __ballot(mk[lane * 4 + b] > 0.5f);
        const unsigned long long sb = __ballot(sg[lane * 4 + b] > 0.5f);
        if (lane == 0) {
            ulonglong2 v; v.x = mb; v.y = sb;
            pk[(((size_t)b * 16 + (i >> 6)) * JT + jt) * 64 + (i & 63)] = v;
        }
    }
}

// ---------------------------------------------------------------------------
// Fused projection uber-GEMM: all 4 projections (q/k/v/kr) in ONE launch.
// m97-style glds staging, 128x128 tile, BK=32.
// MODE 1: fp32 scatter [b][n][seq][d].  MODE 2: bf16 scatter [b][n][seq][d].
// ---------------------------------------------------------------------------
__global__ __launch_bounds__(256) void proj_kernel(
    const u16* __restrict__ hb, const u16* __restrict__ catb,
    const u16* __restrict__ rb,
    const u16* __restrict__ WqT, const u16* __restrict__ WkT,
    const u16* __restrict__ WvT, const u16* __restrict__ WrT,
    float* __restrict__ q_s, u16* __restrict__ k_s,
    u16* __restrict__ v_s, u16* __restrict__ kr_s)
{
    __shared__ u16 a_lds[128][32];   // unpadded: required by global_load_lds
    __shared__ u16 b_lds[128][32];
    const int id = blockIdx.x;
    const u16 *A, *B; void* C; int SEQ, MODE, local;
    if (id < 256)       { A = hb;   B = WqT; C = q_s;  SEQ = QL; MODE = 1; local = id; }
    else if (id < 640)  { A = catb; B = WkT; C = k_s;  SEQ = KL; MODE = 2; local = id - 256; }
    else if (id < 1024) { A = catb; B = WvT; C = v_s;  SEQ = KL; MODE = 2; local = id - 640; }
    else                { A = rb;   B = WrT; C = kr_s; SEQ = RL; MODE = 2; local = id - 1024; }
    const int bm = local >> 3, bnn = local & 7;

    const int t = threadIdx.x;
    const int w = t >> 6, lane = t & 63, l15 = lane & 15, q4 = lane >> 4;
    const int wm = (w >> 1) * 64, wn = (w & 1) * 64;
    const int srow = w * 32 + (lane >> 2);
    const int scol = (lane & 3) * 8;
    const u16* Ab = A + (size_t)(bm * 128 + srow) * DM + scol;
    const u16* Bb = B + (size_t)(bnn * 128 + srow) * DM + scol;
    u16* a_dst = &a_lds[w * 32][0];
    u16* b_dst = &b_lds[w * 32][0];

    f32x4 acc[4][4] = {};

    for (int k0 = 0; k0 < DM; k0 += 32) {
        __syncthreads();
        glds16(Ab + k0,           a_dst);
        glds16(Ab + k0 + 16 * DM, a_dst + 16 * 32);
        glds16(Bb + k0,           b_dst);
        glds16(Bb + k0 + 16 * DM, b_dst + 16 * 32);
        __syncthreads();
        bf16x8 af[4], bf[4];
        #pragma unroll
        for (int rt = 0; rt < 4; rt++)
            af[rt] = *(const bf16x8*)&a_lds[wm + rt * 16 + l15][q4 * 8];
        #pragma unroll
        for (int ct = 0; ct < 4; ct++)
            bf[ct] = *(const bf16x8*)&b_lds[wn + ct * 16 + l15][q4 * 8];
        #pragma unroll
        for (int rt = 0; rt < 4; rt++)
            #pragma unroll
            for (int ct = 0; ct < 4; ct++)
                acc[rt][ct] = __builtin_amdgcn_mfma_f32_16x16x32_bf16(
                    af[rt], bf[ct], acc[rt][ct], 0, 0, 0);
    }

    #pragma unroll
    for (int rt = 0; rt < 4; rt++)
      #pragma unroll
      for (int ct = 0; ct < 4; ct++)
        #pragma unroll
        for (int rg = 0; rg < 4; rg++) {
            const int R = bm * 128 + wm + rt * 16 + q4 * 4 + rg;   // seq*4+b
            const int Cc = bnn * 128 + wn + ct * 16 + l15;         // n*64+d
            const float v = acc[rt][ct][rg];
            const int sq = R >> 2, bb = R & 3, hn = Cc >> 6, dd = Cc & 63;
            const size_t idx = ((size_t)(bb * NH + hn) * SEQ + sq) * DH + dd;
            if (MODE == 1) ((float*)C)[idx] = v;
            else           ((u16*)C)[idx]  = f2bf(v);
        }
}

// ---------------------------------------------------------------------------
// v [b][n][j][d] -> vt [b][n][d][j], 64x64 LDS tile transpose.
// ---------------------------------------------------------------------------
__global__ __launch_bounds__(256) void vtrans_kernel(
    const u16* __restrict__ v_s, u16* __restrict__ vt_s)
{
    __shared__ u16 tl[64][72];
    const int j0 = blockIdx.x * 64;
    const int bn = blockIdx.y;
    const u16* vin = v_s + (size_t)bn * KL * DH;
    u16* vout = vt_s + (size_t)bn * DH * KL;
    const int t = threadIdx.x;
    const int r = t >> 3, c8 = (t & 7) * 8;
    #pragma unroll
    for (int it = 0; it < 64; it += 32)
        *(uint4*)&tl[r + it][c8] = *(const uint4*)(vin + (size_t)(j0 + r + it) * DH + c8);
    __syncthreads();
    #pragma unroll
    for (int it = 0; it < 64; it += 32) {
        const int d = r + it;
        u16 tmp[8];
        #pragma unroll
        for (int jj = 0; jj < 8; jj++) tmp[jj] = tl[c8 + jj][d];
        *(uint4*)&vout[(size_t)d * KL + j0 + c8] = *(const uint4*)tmp;
    }
}

// ---------------------------------------------------------------------------
// Out-projection GEMM (fp32 row-major out), m97-style staging.
// ---------------------------------------------------------------------------
__global__ __launch_bounds__(256) void ogemm_kernel(
    const u16* __restrict__ A, const u16* __restrict__ B,
    float* __restrict__ Cout)
{
    __shared__ u16 a_lds[128][32];
    __shared__ u16 b_lds[128][32];
    const int bm = blockIdx.x, bnn = blockIdx.y;
    const int t = threadIdx.x;
    const int w = t >> 6, lane = t & 63, l15 = lane & 15, q4 = lane >> 4;
    const int wm = (w >> 1) * 64, wn = (w & 1) * 64;
    const int srow = w * 32 + (lane >> 2);
    const int scol = (lane & 3) * 8;
    const u16* Ab = A + (size_t)(bm * 128 + srow) * DM + scol;
    const u16* Bb = B + (size_t)(bnn * 128 + srow) * DM + scol;
    u16* a_dst = &a_lds[w * 32][0];
    u16* b_dst = &b_lds[w * 32][0];

    f32x4 acc[4][4] = {};

    for (int k0 = 0; k0 < DM; k0 += 32) {
        __syncthreads();
        glds16(Ab + k0,           a_dst);
        glds16(Ab + k0 + 16 * DM, a_dst + 16 * 32);
        glds16(Bb + k0,           b_dst);
        glds16(Bb + k0 + 16 * DM, b_dst + 16 * 32);
        __syncthreads();
        bf16x8 af[4], bf[4];
        #pragma unroll
        for (int rt = 0; rt < 4; rt++)
            af[rt] = *(const bf16x8*)&a_lds[wm + rt * 16 + l15][q4 * 8];
        #pragma unroll
        for (int ct = 0; ct < 4; ct++)
            bf[ct] = *(const bf16x8*)&b_lds[wn + ct * 16 + l15][q4 * 8];
        #pragma unroll
        for (int rt = 0; rt < 4; rt++)
            #pragma unroll
            for (int ct = 0; ct < 4; ct++)
                acc[rt][ct] = __builtin_amdgcn_mfma_f32_16x16x32_bf16(
                    af[rt], bf[ct], acc[rt][ct], 0, 0, 0);
    }

    #pragma unroll
    for (int rt = 0; rt < 4; rt++)
      #pragma unroll
      for (int ct = 0; ct < 4; ct++)
        #pragma unroll
        for (int rg = 0; rg < 4; rg++) {
            const int R = bm * 128 + wm + rt * 16 + q4 * 4 + rg;
            const int C = bnn * 128 + wn + ct * 16 + l15;
            Cout[(size_t)R * DM + C] = acc[rt][ct][rg];
        }
}

// ---------------------------------------------------------------------------
// Fused relative attention — round 9: r1's deep pipeline + kr ring-4.
//   Structure (the r1/r3 A/B winner): 2 barriers per phase (both at the
//   seam), EVERYTHING staged 2 tiles ahead, ONE counted vmcnt(7) per phase
//   (never drains mid-loop) -> every load gets a full phase (~1200cy) of
//   compute cover.
//   vs r1: kr full-window restage (4 ops, 2x traffic) -> ring-4 of 64-row
//   panels (2 ops); pk mp regs -> pk_lds dbuf (kills scratch); per-phase
//   staging 12 -> 7 ops. vs r3: no mid-phase barrier, no shallow drains.
//   Softmax trims: SCALE*log2e folded into q/e bf16 fragments (-16 vmul),
//   mask folded pre-exp (-1e30 + exp2 underflow -> exact 0), ef values in
//   registers (-8 LDS reads/phase), __builtin_amdgcn_exp2f fast path.
//   LDS 74.5 KB -> 2 blocks/CU (depth > occupancy per the r1/r3 A/B).
// grid = (64 bn, 16 itile): XCD = bn%8 locality swizzle unchanged.
// ---------------------------------------------------------------------------
#define FBAR() do { asm volatile("" ::: "memory");  \
                    __builtin_amdgcn_s_barrier();   \
                    asm volatile("" ::: "memory"); } while (0)

// stage k tile TI into k2[TI&1] (granule-swizzled source). 2 ops.
#define STAGE_K(TI)                                                            \
  {                                                                            \
    glds16(kg + (size_t)(TI) * 64 * DH,      &k2[(TI) & 1][0][w * 16][0]);     \
    glds16(kg + (size_t)(TI) * 64 * DH + 32, &k2[(TI) & 1][1][w * 16][0]);     \
  }

// stage v tile TI into v2[TI&1]. 2 ops.
#define STAGE_V(TI)                                                            \
  {                                                                            \
    glds16(vg + (TI) * 64,      &v2[(TI) & 1][0][w * 16][0]);                  \
    glds16(vg + (TI) * 64 + 32, &v2[(TI) & 1][1][w * 16][0]);                  \
  }

// stage pk words for tile TI (all 4 waves duplicate; coalesced 1KB). 1 op.
#define STAGE_PK(TI)                                                           \
    glds16((const u16*)(pk_b + ((size_t)(TI) * 64 + lane)),                    \
           (u16*)&pk_lds[(TI) & 1][0]);

// stage kr panel P (64 rows x 64 d, seg-XOR swizzled) into ring slot P&3. 2 ops.
#define STAGE_KR(P)                                                            \
  {                                                                            \
    const int br_ = QL - i0 - 63 + (P) * 64 + w * 16 + krow;                   \
    glds16(kr_bn + (size_t)br_ * DH + ksrcseg * 8,       &krp[(P) & 3][w * 16][0]);     \
    glds16(kr_bn + (size_t)(br_ + 8) * DH + ksrcseg * 8, &krp[(P) & 3][w * 16 + 8][0]); \
  }

__global__ __launch_bounds__(256, 2) void attn_kernel(
    const float* __restrict__ q_s, const u16* __restrict__ k_s,
    const u16* __restrict__ vt_s, const u16* __restrict__ kr_s,
    const ulonglong2* __restrict__ pk,
    const float* __restrict__ rwb, const float* __restrict__ rrb,
    const float* __restrict__ rsb, const float* __restrict__ seg_embed,
    u16* __restrict__ av_s)
{
    __shared__ u16 k2[2][2][64][32];      // 16 KB [buf][half][j][d-swz]
    __shared__ u16 v2[2][2][64][32];      // 16 KB [buf][half][d][j-swz]
    __shared__ u16 krp[4][64][64];        // 32 KB kr ring panels (seg-swz)
    __shared__ u16 p_lds[4][16][64];      // 8 KB, granule-XOR swizzled
    __shared__ ulonglong2 pk_lds[2][64];  // 2 KB [buf][i-row] {mask,seg}
    __shared__ float e_lds[2][64];        // 0.5 KB

    const int bn = blockIdx.x;           // b*16 + n  (fast dim -> XCD = bn%8)
    const int itile = blockIdx.y;
    const int b = bn >> 4, n = bn & 15;
    const int t = threadIdx.x;
    const int w = t >> 6, lane = t & 63, l15 = lane & 15, q4 = lane >> 4;
    const int i0 = itile * 64;
    const int ib = i0 + w * 16;

    const float* q_bn = q_s + (size_t)bn * QL * DH;
    const u16* k_bn   = k_s  + (size_t)bn * KL * DH;
    const u16* vt_bn  = vt_s + (size_t)bn * DH * KL;
    const u16* kr_bn  = kr_s + (size_t)bn * RL * DH;
    const ulonglong2* pk_b = pk + ((size_t)b * 16 + itile) * JT * 64;

    // ef pre-dots, pre-scaled by SC2: e_lds[s][row] = (q+r_s_bias).seg_emb*SC2
    if (t < 128) {
        const int rr = t >> 1, s = t & 1;
        const float* qrow = q_bn + (size_t)(i0 + rr) * DH;
        const float* se = seg_embed + (s * NH + n) * DH;
        const float* bias = rsb + n * DH;
        float acc = 0.f;
        #pragma unroll 16
        for (int d = 0; d < DH; d++) acc += (qrow[d] + bias[d]) * se[d];
        e_lds[s][rr] = acc * SC2;
    }

    // q fragments (A-layout), biases folded, PRE-SCALED by SC2 so the
    // score is exp2-ready without a per-element multiply.
    bf16x8 qw[2], qr[2];
    {
        const float* qrow = q_bn + (size_t)(ib + l15) * DH;
        const float* bw = rwb + n * DH;
        const float* br = rrb + n * DH;
        #pragma unroll
        for (int kk = 0; kk < 2; kk++) {
            const int dbase = kk * 32 + q4 * 8;
            #pragma unroll
            for (int j = 0; j < 8; j++) {
                float qv = qrow[dbase + j];
                qw[kk][j] = (short)f2bf((qv + bw[dbase + j]) * SC2);
                qr[kk][j] = (short)f2bf((qv + br[dbase + j]) * SC2);
            }
        }
    }

    // k/v staging lane coords (16 rows per glds, 4 lanes x 16B per row).
    // Source granule pre-swizzled by (row>>1)&3; reads XOR the same way.
    const int srow = lane >> 2;
    const int ssw  = ((lane & 3) ^ ((srow >> 1) & 3)) * 8;
    const u16* kg = k_bn  + (size_t)(w * 16 + srow) * DH + ssw;
    const u16* vg = vt_bn + (size_t)(w * 16 + srow) * KL + ssw;

    // kr staging coords: 8 rows per glds; seg-XOR swizzle s^(r&7).
    const int krow = lane >> 3;
    const int ksrcseg = (lane & 7) ^ krow;

    // bd read swizzle offsets; k/v read granule swizzle
    const int sA = ((q4)     ^ (l15 & 7)) * 8;   // kk=0 seg offset (elems)
    const int sB = ((q4 + 4) ^ (l15 & 7)) * 8;   // kk=1
    const int ksw = (l15 >> 1) & 3;
    const int lrb_p = 48 - w * 16;               // window base offset (0..48)

    f32x4 o[4] = {};
    float l_r[4] = {0.f, 0.f, 0.f, 0.f};

    // ---- prologue: tiles 0,1 fully staged + kr panels 0,1,2.
    //      issue order: [phase-0 needs (9)] then [phase-1 prestage (7)];
    //      vmcnt(7) -> first 9 complete, 7 newest stay in flight.
    STAGE_K(0); STAGE_V(0); STAGE_PK(0);
    STAGE_KR(0); STAGE_KR(1);
    STAGE_K(1); STAGE_V(1); STAGE_PK(1);
    STAGE_KR(2);
    asm volatile("s_waitcnt vmcnt(7) lgkmcnt(0)" ::: "memory");
    FBAR();

    // ef values to registers (e_lds is read-only from here on)
    float e_rg[2][4];
    #pragma unroll
    for (int rg = 0; rg < 4; rg++) {
        e_rg[0][rg] = e_lds[0][w * 16 + q4 * 4 + rg];
        e_rg[1][rg] = e_lds[1][w * 16 + q4 * 4 + rg];
    }

    // ---- main loop: zero mid-phase barriers; 2 barriers + 1 counted
    //      vmcnt at the seam. ----
    #pragma unroll 1
    for (int jt = 0; jt < JT; jt++) {
        const int cb = jt & 1;

        // ---- ac = (q + r_w_bias) . K^T ----
        __builtin_amdgcn_s_setprio(1);
        f32x4 sac[4] = {};
        #pragma unroll
        for (int ct = 0; ct < 4; ct++) {
            bf16x8 kb0 = *(const bf16x8*)&k2[cb][0][ct * 16 + l15][(q4 ^ ksw) * 8];
            bf16x8 kb1 = *(const bf16x8*)&k2[cb][1][ct * 16 + l15][(q4 ^ ksw) * 8];
            sac[ct] = __builtin_amdgcn_mfma_f32_16x16x32_bf16(qw[0], kb0, sac[ct], 0, 0, 0);
            sac[ct] = __builtin_amdgcn_mfma_f32_16x16x32_bf16(qw[1], kb1, sac[ct], 0, 0, 0);
        }

        // ---- bd window MFMAs (B-frags from ring panels jt, jt+1) ----
        f32x4 bacc[5] = {};
        #pragma unroll
        for (int wc = 0; wc < 5; wc++) {
            const int S = lrb_p + wc * 16;               // 0..112, no 64-cross
            const u16* pr_ = &krp[(jt + (S >> 6)) & 3][(S & 63) + l15][0];
            bf16x8 b0 = *(const bf16x8*)(pr_ + sA);
            bf16x8 b1 = *(const bf16x8*)(pr_ + sB);
            bacc[wc] = __builtin_amdgcn_mfma_f32_16x16x32_bf16(qr[0], b0, bacc[wc], 0, 0, 0);
            bacc[wc] = __builtin_amdgcn_mfma_f32_16x16x32_bf16(qr[1], b1, bacc[wc], 0, 0, 0);
        }
        __builtin_amdgcn_s_setprio(0);

        // ---- band extract + scores + exp2 + swizzled P-store ----
        #pragma unroll
        for (int rg = 0; rg < 4; rg++) {
            const int row = q4 * 4 + rg;
            const ulonglong2 mp = pk_lds[cb][w * 16 + row];
            const unsigned long long mx = mp.x >> l15;
            const unsigned long long sy = mp.y >> l15;
            const int v = l15 + 15 - row;          // in [0,30]
            const int srcl = (q4 << 4) | (v & 15);
            float sh[5];
            #pragma unroll
            for (int w5 = 0; w5 < 5; w5++)
                sh[w5] = __shfl(bacc[w5][rg], srcl, 64);
            const float e0 = e_rg[0][rg];
            const float e1 = e_rg[1][rg];
            float s0 = 0.f;
            #pragma unroll
            for (int ct = 0; ct < 4; ct++) {
                const float bd = (v < 16) ? sh[ct] : sh[ct + 1];
                const float ef = ((sy >> (ct * 16)) & 1ull) ? e1 : e0;
                float sarg = sac[ct][rg] + bd + ef;
                sarg = ((mx >> (ct * 16)) & 1ull) ? -1.0e30f : sarg;
                const float p = __builtin_amdgcn_exp2f(sarg);   // masked -> +0
                const int pg = (2 * ct + (l15 >> 3)) ^ (row & 7);
                p_lds[w][row][pg * 8 + (l15 & 7)] = f2bf(p);
                s0 += p;
            }
            l_r[rg] += s0;
        }

        // ---- PV MFMA (P read back in A-layout, same wave; V from LDS) ----
        __builtin_amdgcn_s_setprio(1);
        #pragma unroll
        for (int kk = 0; kk < 2; kk++) {
            const int pgr = ((kk * 4 + q4) ^ (l15 & 7)) * 8;
            bf16x8 pf = *(const bf16x8*)&p_lds[w][l15][pgr];
            #pragma unroll
            for (int dt = 0; dt < 4; dt++) {
                bf16x8 vf = *(const bf16x8*)&v2[cb][kk][dt * 16 + l15][(q4 ^ ksw) * 8];
                o[dt] = __builtin_amdgcn_mfma_f32_16x16x32_bf16(pf, vf, o[dt], 0, 0, 0);
            }
        }
        __builtin_amdgcn_s_setprio(0);

        // ---- seam: all buffers for jt consumed; stage jt+2 (and panel
        //      jt+3), counted wait confirms jt+1's 7 ops (full-phase cover).
        if (jt < JT - 1) {
            FBAR();
            if (jt + 2 < JT) {
                STAGE_K(jt + 2);
                STAGE_V(jt + 2);
                STAGE_PK(jt + 2);
                STAGE_KR(jt + 3);
                asm volatile("s_waitcnt vmcnt(7)" ::: "memory");
            } else {
                asm volatile("s_waitcnt vmcnt(0)" ::: "memory");
            }
            FBAR();
        }
    }

    // ---- epilogue: quad-reduce l_r once, normalize, write attn_vec ----
    #pragma unroll
    for (int rg = 0; rg < 4; rg++) {
        #pragma unroll
        for (int off = 1; off < 16; off <<= 1)
            l_r[rg] += __shfl_xor(l_r[rg], off, 64);
        l_r[rg] = 1.f / l_r[rg];
    }
    #pragma unroll
    for (int dt = 0; dt < 4; dt++)
        #pragma unroll
        for (int rg = 0; rg < 4; rg++) {
            const int row = q4 * 4 + rg;
            const int ii = ib + row;
            const int d = dt * 16 + l15;
            const float v = o[dt][rg] * l_r[rg];
            av_s[(size_t)(ii * BS + b) * DM + n * DH + d] = f2bf(v);
        }
}

// ---------------------------------------------------------------------------
// Residual + LayerNorm: out = LN(ao + h) * gamma + beta. One block per row.
// ---------------------------------------------------------------------------
__global__ __launch_bounds__(256) void ln_kernel(
    const float* __restrict__ ao, const float* __restrict__ h,
    const float* __restrict__ gamma, const float* __restrict__ beta,
    float* __restrict__ out)
{
    __shared__ float red[8];
    const int row = blockIdx.x, t = threadIdx.x;
    const float* a  = ao + (size_t)row * DM;
    const float* hh = h  + (size_t)row * DM;
    float4 av = *(const float4*)(a + t * 4);
    float4 hv = *(const float4*)(hh + t * 4);
    const float x0 = av.x + hv.x, x1 = av.y + hv.y;
    const float x2 = av.z + hv.z, x3 = av.w + hv.w;
    float s = x0 + x1 + x2 + x3;
    float s2 = x0 * x0 + x1 * x1 + x2 * x2 + x3 * x3;
    #pragma unroll
    for (int off = 1; off < 64; off <<= 1) {
        s  += __shfl_xor(s, off, 64);
        s2 += __shfl_xor(s2, off, 64);
    }
    const int w = t >> 6;
    if ((t & 63) == 0) { red[w] = s; red[4 + w] = s2; }
    __syncthreads();
    s  = red[0] + red[1] + red[2] + red[3];
    s2 = red[4] + red[5] + red[6] + red[7];
    const float mu = s * (1.f / DM);
    const float var = s2 * (1.f / DM) - mu * mu;
    const float rstd = rsqrtf(var + 1e-12f);
    float4 g  = *(const float4*)(gamma + t * 4);
    float4 bb = *(const float4*)(beta + t * 4);
    float4 ov;
    ov.x = (x0 - mu) * rstd * g.x + bb.x;
    ov.y = (x1 - mu) * rstd * g.y + bb.y;
    ov.z = (x2 - mu) * rstd * g.z + bb.z;
    ov.w = (x3 - mu) * rstd * g.w + bb.w;
    *(float4*)(out + (size_t)row * DM + t * 4) = ov;
}

// ---------------------------------------------------------------------------
extern "C" void kernel_launch(void* const* d_in, const int* in_sizes, int n_in,
                              void* d_out, int out_size, void* d_ws, size_t ws_size,
                              hipStream_t stream) {
    (void)in_sizes; (void)n_in; (void)out_size; (void)ws_size;
    const float* h    = (const float*)d_in[0];
    const float* r    = (const float*)d_in[1];
    const float* mems = (const float*)d_in[2];
    const float* mask = (const float*)d_in[3];
    const float* segm = (const float*)d_in[4];
    const float* Wq   = (const float*)d_in[5];
    const float* Wk   = (const float*)d_in[6];
    const float* Wv   = (const float*)d_in[7];
    const float* Wo   = (const float*)d_in[8];
    const float* Wr   = (const float*)d_in[9];
    const float* rwb  = (const float*)d_in[10];
    const float* rrb  = (const float*)d_in[11];
    const float* rsb  = (const float*)d_in[12];
    const float* semb = (const float*)d_in[13];
    const float* gam  = (const float*)d_in[14];
    const float* bet  = (const float*)d_in[15];
    float* out = (float*)d_out;

    char* wsb = (char*)d_ws;
    size_t off = 0;
    auto alloc = [&](size_t bytes) -> void* {
        void* p = wsb + off; off += (bytes + 255) & ~(size_t)255; return p;
    };
    u16* catb = (u16*)alloc((size_t)KL * BS * DM * 2);
    u16* rb   = (u16*)alloc((size_t)RL * BS * DM * 2);
    u16* WqT  = (u16*)alloc((size_t)DM * DM * 2);
    u16* WkT  = (u16*)alloc((size_t)DM * DM * 2);
    u16* WvT  = (u16*)alloc((size_t)DM * DM * 2);
    u16* WrT  = (u16*)alloc((size_t)DM * DM * 2);
    u16* WoB  = (u16*)alloc((size_t)DM * DM * 2);
    float* q_s = (float*)alloc((size_t)BS * NH * QL * DH * 4);
    u16* k_s  = (u16*)alloc((size_t)BS * NH * KL * DH * 2);
    u16* vt_s = (u16*)alloc((size_t)BS * NH * KL * DH * 2);
    u16* kr_s = (u16*)alloc((size_t)BS * NH * RL * DH * 2 + 8192); // tail pad: kr window over-read
    u16* av_s = (u16*)alloc((size_t)QL * BS * DM * 2);
    float* ao_s = (float*)alloc((size_t)QL * BS * DM * 4);
    ulonglong2* pk = (ulonglong2*)alloc((size_t)BS * QL * JT * 16);
    u16* v_s = (u16*)ao_s;   // alias: v_s dead before ao_s is written

    // 1) fused prep: convert + W transpose + mask/seg pack (one launch)
    prep_kernel<<<43008, 256, 0, stream>>>(mems, h, r, Wo, mask, segm,
                                           Wq, Wk, Wv, Wr,
                                           catb, rb, WoB,
                                           WqT, WkT, WvT, WrT, pk);
    // 2) all 4 projections in one launch (hb = h part of catb)
    const u16* hb = catb + (size_t)2048 * DM;
    proj_kernel<<<1664, 256, 0, stream>>>(hb, catb, rb, WqT, WkT, WvT, WrT,
                                          q_s, k_s, v_s, kr_s);
    // 2b) v -> v^T
    vtrans_kernel<<<dim3(JT, 64), 256, 0, stream>>>(v_s, vt_s);
    // 3) fused attention — grid (bn, itile): XCD = bn%8 locality swizzle
    attn_kernel<<<dim3(64, 16), 256, 0, stream>>>(q_s, k_s, vt_s, kr_s, pk,
                                                  rwb, rrb, rsb, semb, av_s);
    // 4) output projection + residual layernorm
    ogemm_kernel<<<dim3(32, 8), 256, 0, stream>>>(av_s, WoB, ao_s);
    ln_kernel<<<4096, 256, 0, stream>>>(ao_s, h, gam, bet, out);
}

// Round 5
// 480.322 us; speedup vs baseline: 1.0718x; 1.0718x over previous
//
#include <hip/hip_runtime.h>

typedef unsigned short u16;
typedef __attribute__((ext_vector_type(8))) short bf16x8;
typedef __attribute__((ext_vector_type(4))) float f32x4;

constexpr int DM = 1024;   // d_model
constexpr int NH = 16;     // n_head
constexpr int DH = 64;     // d_head
constexpr int QL = 1024;   // qlen
constexpr int ML = 512;    // mlen
constexpr int KL = 1536;   // klen = qlen + mlen
constexpr int RL = 2560;   // rlen = qlen + klen
constexpr int BS = 4;      // batch
constexpr int JT = KL / 64;  // 24 j-tiles of 64
constexpr float SCALE = 0.125f;  // 1/sqrt(64)
constexpr float SC2 = 0.125f * 1.4426950408889634f;  // SCALE * log2(e)

static __device__ __forceinline__ u16 f2bf(float f) {
    unsigned u = __float_as_uint(f);
    u += 0x7fffu + ((u >> 16) & 1u);   // RNE
    return (u16)(u >> 16);
}

// async global->LDS DMA, 16B per lane. LDS dest = wave-uniform base + lane*16.
// Global source address is PER-LANE (gather allowed).
static __device__ __forceinline__ void glds16(const u16* g, u16* l) {
    __builtin_amdgcn_global_load_lds(
        (const __attribute__((address_space(1))) unsigned int*)g,
        (__attribute__((address_space(3))) unsigned int*)l,
        16, 0, 0);
}

// ---------------------------------------------------------------------------
// Fused prep (1 launch): blocks [0,17408) fp32->bf16 convert of cat/r/Wo;
// [17408,18432) W transpose-convert; [18432,43008) mask/seg bit-pack.
// pk layout: [b][itile128][jt][row0..127] (two coalesced 1KB gathers/tile).
// ---------------------------------------------------------------------------
__global__ __launch_bounds__(256) void prep_kernel(
    const float* __restrict__ mems, const float* __restrict__ h,
    const float* __restrict__ r, const float* __restrict__ Wo,
    const float* __restrict__ mask, const float* __restrict__ segm,
    const float* __restrict__ Wq, const float* __restrict__ Wk,
    const float* __restrict__ Wv, const float* __restrict__ Wr,
    u16* __restrict__ catb, u16* __restrict__ rb, u16* __restrict__ wob,
    u16* __restrict__ WqT, u16* __restrict__ WkT,
    u16* __restrict__ WvT, u16* __restrict__ WrT,
    ulonglong2* __restrict__ pk)
{
    __shared__ float smem[64 * 65];
    const int id = blockIdx.x;
    const int t = threadIdx.x;

    if (id < 17408) {        // ---- convert ----
        const long C0 = (long)ML * BS * DM;
        const long C1 = (long)KL * BS * DM;
        const long C2 = C1 + (long)RL * BS * DM;
        long g = ((long)id * 256 + t) * 4;
        const float* src; u16* dst;
        if (g < C0)      { src = mems + g;        dst = catb + g; }
        else if (g < C1) { src = h + (g - C0);    dst = catb + g; }
        else if (g < C2) { src = r + (g - C1);    dst = rb + (g - C1); }
        else             { src = Wo + (g - C2);   dst = wob + (g - C2); }
        float4 v = *(const float4*)src;
        unsigned lo = (unsigned)f2bf(v.x) | ((unsigned)f2bf(v.y) << 16);
        unsigned hi = (unsigned)f2bf(v.z) | ((unsigned)f2bf(v.w) << 16);
        *(uint2*)dst = make_uint2(lo, hi);
        return;
    }
    if (id < 18432) {        // ---- W transpose ----
        float (*tile)[65] = (float(*)[65])smem;
        const int local = id - 17408;
        const float* W; u16* WT;
        switch (local >> 8) {
            case 0:  W = Wq; WT = WqT; break;
            case 1:  W = Wk; WT = WkT; break;
            case 2:  W = Wv; WT = WvT; break;
            default: W = Wr; WT = WrT; break;
        }
        const int k0 = (local & 15) * 64, n0 = ((local >> 4) & 15) * 64;
        const int tr = t >> 6, tc = t & 63;
        #pragma unroll
        for (int rr = 0; rr < 16; rr++) {
            int rw = tr + rr * 4;
            tile[rw][tc] = W[(size_t)(k0 + rw) * DM + n0 + tc];
        }
        __syncthreads();
        #pragma unroll
        for (int rr = 0; rr < 16; rr++) {
            int n = tr + rr * 4;
            WT[(size_t)(n0 + n) * DM + k0 + tc] = f2bf(tile[tc][n]);
        }
        return;
    }
    // ---- pack mask/seg bits ----
    {
        float* mk = smem;
        float* sg = smem + 256;
        const int local = id - 18432;
        const int i = local / JT, jt = local - i * JT;
        const size_t base = ((size_t)i * KL + jt * 64) * BS;   // float idx (j*4+b)
        mk[t] = mask[base + t];
        float2 s2 = ((const float2*)(segm + base * 2))[t];
        sg[t] = s2.y;
        __syncthreads();
        const int b = t >> 6, lane = t & 63;
        const unsigned long long mb = __ballot(mk[lane * 4 + b] > 0.5f);
        const unsigned long long sb = __ballot(sg[lane * 4 + b] > 0.5f);
        if (lane == 0) {
            ulonglong2 v; v.x = mb; v.y = sb;
            pk[(((size_t)b * 8 + (i >> 7)) * JT + jt) * 128 + (i & 127)] = v;
        }
    }
}

// ---------------------------------------------------------------------------
// Fused projection uber-GEMM: all 4 projections (q/k/v/kr) in ONE launch.
// m97-style glds staging, 128x128 tile, BK=32.
// MODE 1: fp32 scatter [b][n][seq][d].  MODE 2: bf16 scatter [b][n][seq][d].
// ---------------------------------------------------------------------------
__global__ __launch_bounds__(256) void proj_kernel(
    const u16* __restrict__ hb, const u16* __restrict__ catb,
    const u16* __restrict__ rb,
    const u16* __restrict__ WqT, const u16* __restrict__ WkT,
    const u16* __restrict__ WvT, const u16* __restrict__ WrT,
    float* __restrict__ q_s, u16* __restrict__ k_s,
    u16* __restrict__ v_s, u16* __restrict__ kr_s)
{
    __shared__ u16 a_lds[128][32];   // unpadded: required by global_load_lds
    __shared__ u16 b_lds[128][32];
    const int id = blockIdx.x;
    const u16 *A, *B; void* C; int SEQ, MODE, local;
    if (id < 256)       { A = hb;   B = WqT; C = q_s;  SEQ = QL; MODE = 1; local = id; }
    else if (id < 640)  { A = catb; B = WkT; C = k_s;  SEQ = KL; MODE = 2; local = id - 256; }
    else if (id < 1024) { A = catb; B = WvT; C = v_s;  SEQ = KL; MODE = 2; local = id - 640; }
    else                { A = rb;   B = WrT; C = kr_s; SEQ = RL; MODE = 2; local = id - 1024; }
    const int bm = local >> 3, bnn = local & 7;

    const int t = threadIdx.x;
    const int w = t >> 6, lane = t & 63, l15 = lane & 15, q4 = lane >> 4;
    const int wm = (w >> 1) * 64, wn = (w & 1) * 64;
    const int srow = w * 32 + (lane >> 2);
    const int scol = (lane & 3) * 8;
    const u16* Ab = A + (size_t)(bm * 128 + srow) * DM + scol;
    const u16* Bb = B + (size_t)(bnn * 128 + srow) * DM + scol;
    u16* a_dst = &a_lds[w * 32][0];
    u16* b_dst = &b_lds[w * 32][0];

    f32x4 acc[4][4] = {};

    for (int k0 = 0; k0 < DM; k0 += 32) {
        __syncthreads();
        glds16(Ab + k0,           a_dst);
        glds16(Ab + k0 + 16 * DM, a_dst + 16 * 32);
        glds16(Bb + k0,           b_dst);
        glds16(Bb + k0 + 16 * DM, b_dst + 16 * 32);
        __syncthreads();
        bf16x8 af[4], bf[4];
        #pragma unroll
        for (int rt = 0; rt < 4; rt++)
            af[rt] = *(const bf16x8*)&a_lds[wm + rt * 16 + l15][q4 * 8];
        #pragma unroll
        for (int ct = 0; ct < 4; ct++)
            bf[ct] = *(const bf16x8*)&b_lds[wn + ct * 16 + l15][q4 * 8];
        #pragma unroll
        for (int rt = 0; rt < 4; rt++)
            #pragma unroll
            for (int ct = 0; ct < 4; ct++)
                acc[rt][ct] = __builtin_amdgcn_mfma_f32_16x16x32_bf16(
                    af[rt], bf[ct], acc[rt][ct], 0, 0, 0);
    }

    #pragma unroll
    for (int rt = 0; rt < 4; rt++)
      #pragma unroll
      for (int ct = 0; ct < 4; ct++)
        #pragma unroll
        for (int rg = 0; rg < 4; rg++) {
            const int R = bm * 128 + wm + rt * 16 + q4 * 4 + rg;   // seq*4+b
            const int Cc = bnn * 128 + wn + ct * 16 + l15;         // n*64+d
            const float v = acc[rt][ct][rg];
            const int sq = R >> 2, bb = R & 3, hn = Cc >> 6, dd = Cc & 63;
            const size_t idx = ((size_t)(bb * NH + hn) * SEQ + sq) * DH + dd;
            if (MODE == 1) ((float*)C)[idx] = v;
            else           ((u16*)C)[idx]  = f2bf(v);
        }
}

// ---------------------------------------------------------------------------
// v [b][n][j][d] -> vt [b][n][d][j], 64x64 LDS tile transpose.
// ---------------------------------------------------------------------------
__global__ __launch_bounds__(256) void vtrans_kernel(
    const u16* __restrict__ v_s, u16* __restrict__ vt_s)
{
    __shared__ u16 tl[64][72];
    const int j0 = blockIdx.x * 64;
    const int bn = blockIdx.y;
    const u16* vin = v_s + (size_t)bn * KL * DH;
    u16* vout = vt_s + (size_t)bn * DH * KL;
    const int t = threadIdx.x;
    const int r = t >> 3, c8 = (t & 7) * 8;
    #pragma unroll
    for (int it = 0; it < 64; it += 32)
        *(uint4*)&tl[r + it][c8] = *(const uint4*)(vin + (size_t)(j0 + r + it) * DH + c8);
    __syncthreads();
    #pragma unroll
    for (int it = 0; it < 64; it += 32) {
        const int d = r + it;
        u16 tmp[8];
        #pragma unroll
        for (int jj = 0; jj < 8; jj++) tmp[jj] = tl[c8 + jj][d];
        *(uint4*)&vout[(size_t)d * KL + j0 + c8] = *(const uint4*)tmp;
    }
}

// ---------------------------------------------------------------------------
// Out-projection GEMM (fp32 row-major out), m97-style staging.
// ---------------------------------------------------------------------------
__global__ __launch_bounds__(256) void ogemm_kernel(
    const u16* __restrict__ A, const u16* __restrict__ B,
    float* __restrict__ Cout)
{
    __shared__ u16 a_lds[128][32];
    __shared__ u16 b_lds[128][32];
    const int bm = blockIdx.x, bnn = blockIdx.y;
    const int t = threadIdx.x;
    const int w = t >> 6, lane = t & 63, l15 = lane & 15, q4 = lane >> 4;
    const int wm = (w >> 1) * 64, wn = (w & 1) * 64;
    const int srow = w * 32 + (lane >> 2);
    const int scol = (lane & 3) * 8;
    const u16* Ab = A + (size_t)(bm * 128 + srow) * DM + scol;
    const u16* Bb = B + (size_t)(bnn * 128 + srow) * DM + scol;
    u16* a_dst = &a_lds[w * 32][0];
    u16* b_dst = &b_lds[w * 32][0];

    f32x4 acc[4][4] = {};

    for (int k0 = 0; k0 < DM; k0 += 32) {
        __syncthreads();
        glds16(Ab + k0,           a_dst);
        glds16(Ab + k0 + 16 * DM, a_dst + 16 * 32);
        glds16(Bb + k0,           b_dst);
        glds16(Bb + k0 + 16 * DM, b_dst + 16 * 32);
        __syncthreads();
        bf16x8 af[4], bf[4];
        #pragma unroll
        for (int rt = 0; rt < 4; rt++)
            af[rt] = *(const bf16x8*)&a_lds[wm + rt * 16 + l15][q4 * 8];
        #pragma unroll
        for (int ct = 0; ct < 4; ct++)
            bf[ct] = *(const bf16x8*)&b_lds[wn + ct * 16 + l15][q4 * 8];
        #pragma unroll
        for (int rt = 0; rt < 4; rt++)
            #pragma unroll
            for (int ct = 0; ct < 4; ct++)
                acc[rt][ct] = __builtin_amdgcn_mfma_f32_16x16x32_bf16(
                    af[rt], bf[ct], acc[rt][ct], 0, 0, 0);
    }

    #pragma unroll
    for (int rt = 0; rt < 4; rt++)
      #pragma unroll
      for (int ct = 0; ct < 4; ct++)
        #pragma unroll
        for (int rg = 0; rg < 4; rg++) {
            const int R = bm * 128 + wm + rt * 16 + q4 * 4 + rg;
            const int C = bnn * 128 + wn + ct * 16 + l15;
            Cout[(size_t)R * DM + C] = acc[rt][ct][rg];
        }
}

// ---------------------------------------------------------------------------
// Fused relative attention — round 10: 128-row i-tiles (2x work per phase).
//   Each block owns 128 q-rows; wave = 32 rows as two independent 16-row
//   groups -> per-phase barrier/staging cost amortized 2x, softmax chains
//   of the two groups interleave (ILP where it's scarcest).
//   Grid 64 bn x 8 itiles = 512 blocks = exact residency (1 round, no tail).
//   LDS 77.25K -> 2 blocks/CU: k2 dbuf 16K, v SINGLE 8K (staged at seam,
//   retired at pre-PV via counted vmcnt), kr ring-4 32K (3 panels read per
//   phase; 4th staged at pre-PV under PV+seam cover; kr is L2/XCD-resident),
//   p 16K, pk dbuf 4K, e 1K.
//   vmcnt ledger (in-order retirement), invariant at each phase entry:
//   outstanding = {V(jt) [2, oldest], k(jt+1) [2], pk(jt+1) [2]}.
//     pre-PV: vmcnt(4) retires exactly V(jt); FBAR; stage kr(jt+3) [2].
//     seam:   FBAR; stage V(jt+1) [2], k(jt+2) [2], pk(jt+2) [2];
//             vmcnt(6) retires exactly {k(jt+1), pk(jt+1), kr(jt+3)}; FBAR.
//   Nothing drains mid-loop; every load gets >= PV+phase of cover.
// ---------------------------------------------------------------------------
#define FBAR() do { asm volatile("" ::: "memory");  \
                    __builtin_amdgcn_s_barrier();   \
                    asm volatile("" ::: "memory"); } while (0)

// stage k tile TI into k2[TI&1] (granule-swizzled source). 2 ops.
#define STAGE_K(TI)                                                            \
  {                                                                            \
    glds16(kg + (size_t)(TI) * 64 * DH,      &k2[(TI) & 1][0][w * 16][0]);     \
    glds16(kg + (size_t)(TI) * 64 * DH + 32, &k2[(TI) & 1][1][w * 16][0]);     \
  }

// stage v tile TI into the single v1 buffer. 2 ops.
#define STAGE_V(TI)                                                            \
  {                                                                            \
    glds16(vg + (TI) * 64,      &v1[0][w * 16][0]);                            \
    glds16(vg + (TI) * 64 + 32, &v1[1][w * 16][0]);                            \
  }

// stage pk words for tile TI (128 rows; all 4 waves duplicate). 2 ops.
#define STAGE_PK(TI)                                                           \
  {                                                                            \
    glds16((const u16*)(pk_b + ((size_t)(TI) * 128 + lane)),                   \
           (u16*)&pk_lds[(TI) & 1][0]);                                        \
    glds16((const u16*)(pk_b + ((size_t)(TI) * 128 + 64 + lane)),              \
           (u16*)&pk_lds[(TI) & 1][64]);                                       \
  }

// stage kr panel P (64 rows x 64 d, seg-XOR swizzled) into ring slot P&3. 2 ops.
#define STAGE_KR(P)                                                            \
  {                                                                            \
    const int br_ = PbaseG + (P) * 64 + w * 16 + krow;                         \
    glds16(kr_bn + (size_t)br_ * DH + ksrcseg * 8,       &krp[(P) & 3][w * 16][0]);     \
    glds16(kr_bn + (size_t)(br_ + 8) * DH + ksrcseg * 8, &krp[(P) & 3][w * 16 + 8][0]); \
  }

__global__ __launch_bounds__(256, 2) void attn_kernel(
    const float* __restrict__ q_s, const u16* __restrict__ k_s,
    const u16* __restrict__ vt_s, const u16* __restrict__ kr_s,
    const ulonglong2* __restrict__ pk,
    const float* __restrict__ rwb, const float* __restrict__ rrb,
    const float* __restrict__ rsb, const float* __restrict__ seg_embed,
    u16* __restrict__ av_s)
{
    __shared__ u16 k2[2][2][64][32];      // 16 KB [buf][half][j][d-swz]
    __shared__ u16 v1[2][64][32];         // 8 KB  [half][d][j-swz]  single buf
    __shared__ u16 krp[4][64][64];        // 32 KB kr ring panels (seg-swz)
    __shared__ u16 p_lds[4][32][64];      // 16 KB, granule-XOR swizzled
    __shared__ ulonglong2 pk_lds[2][128]; // 4 KB [buf][i-row] {mask,seg}
    __shared__ float e_lds[2][128];       // 1 KB

    const int bn = blockIdx.x;           // b*16 + n  (fast dim -> XCD = bn%8)
    const int itile = blockIdx.y;        // 8 x 128-row tiles
    const int b = bn >> 4, n = bn & 15;
    const int t = threadIdx.x;
    const int w = t >> 6, lane = t & 63, l15 = lane & 15, q4 = lane >> 4;
    const int i0 = itile * 128;
    const int ib = i0 + w * 32;          // wave's 32 rows
    const int PbaseG = QL - i0 - 127;    // kr window base (jt-independent)

    const float* q_bn = q_s + (size_t)bn * QL * DH;
    const u16* k_bn   = k_s  + (size_t)bn * KL * DH;
    const u16* vt_bn  = vt_s + (size_t)bn * DH * KL;
    const u16* kr_bn  = kr_s + (size_t)bn * RL * DH;
    const ulonglong2* pk_b = pk + ((size_t)b * 8 + itile) * (JT * 128);

    // ef pre-dots, pre-scaled by SC2: 256 threads cover 128 rows x 2 segs.
    {
        const int rr = t >> 1, s = t & 1;
        const float* qrow = q_bn + (size_t)(i0 + rr) * DH;
        const float* se = seg_embed + (s * NH + n) * DH;
        const float* bias = rsb + n * DH;
        float acc = 0.f;
        #pragma unroll 16
        for (int d = 0; d < DH; d++) acc += (qrow[d] + bias[d]) * se[d];
        e_lds[s][rr] = acc * SC2;
    }

    // q fragments for both 16-row groups (A-layout), biases folded, x SC2.
    bf16x8 qw[2][2], qr[2][2];
    #pragma unroll
    for (int g = 0; g < 2; g++) {
        const float* qrow = q_bn + (size_t)(ib + g * 16 + l15) * DH;
        const float* bw = rwb + n * DH;
        const float* br = rrb + n * DH;
        #pragma unroll
        for (int kk = 0; kk < 2; kk++) {
            const int dbase = kk * 32 + q4 * 8;
            #pragma unroll
            for (int j = 0; j < 8; j++) {
                float qv = qrow[dbase + j];
                qw[g][kk][j] = (short)f2bf((qv + bw[dbase + j]) * SC2);
                qr[g][kk][j] = (short)f2bf((qv + br[dbase + j]) * SC2);
            }
        }
    }

    // k/v staging lane coords (16 rows per glds, 4 lanes x 16B per row).
    // Source granule pre-swizzled by (row>>1)&3; reads XOR the same way.
    const int srow = lane >> 2;
    const int ssw  = ((lane & 3) ^ ((srow >> 1) & 3)) * 8;
    const u16* kg = k_bn  + (size_t)(w * 16 + srow) * DH + ssw;
    const u16* vg = vt_bn + (size_t)(w * 16 + srow) * KL + ssw;

    // kr staging coords: 8 rows per glds; seg-XOR swizzle s^(r&7).
    const int krow = lane >> 3;
    const int ksrcseg = (lane & 7) ^ krow;

    // bd read swizzle offsets; k/v read granule swizzle
    const int sA = ((q4)     ^ (l15 & 7)) * 8;   // kk=0 seg offset (elems)
    const int sB = ((q4 + 4) ^ (l15 & 7)) * 8;   // kk=1
    const int ksw = (l15 >> 1) & 3;

    f32x4 o[2][4] = {};
    float l_r[2][4] = {};

    // ---- prologue. Issue order matters for the vmcnt ledger:
    //      [k0,pk0,kr0,kr1,kr2 = 10 ops needed at phase 0] then
    //      [V0 2, k1 2, pk1 2]. vmcnt(6) retires the first 10; the
    //      outstanding set {V0 oldest, k1, pk1} = the loop invariant.
    STAGE_K(0); STAGE_PK(0);
    STAGE_KR(0); STAGE_KR(1); STAGE_KR(2);
    STAGE_V(0); STAGE_K(1); STAGE_PK(1);
    asm volatile("s_waitcnt vmcnt(6) lgkmcnt(0)" ::: "memory");
    FBAR();

    // ef values to registers (e_lds read-only from here on)
    float e_rg[2][2][4];
    #pragma unroll
    for (int g = 0; g < 2; g++)
        #pragma unroll
        for (int rg = 0; rg < 4; rg++) {
            e_rg[0][g][rg] = e_lds[0][w * 32 + g * 16 + q4 * 4 + rg];
            e_rg[1][g][rg] = e_lds[1][w * 32 + g * 16 + q4 * 4 + rg];
        }

    #pragma unroll 1
    for (int jt = 0; jt < JT; jt++) {
        const int cb = jt & 1;

        // ---- ac for both groups (k-frags shared) ----
        __builtin_amdgcn_s_setprio(1);
        f32x4 sac[2][4] = {};
        #pragma unroll
        for (int ct = 0; ct < 4; ct++) {
            bf16x8 kb0 = *(const bf16x8*)&k2[cb][0][ct * 16 + l15][(q4 ^ ksw) * 8];
            bf16x8 kb1 = *(const bf16x8*)&k2[cb][1][ct * 16 + l15][(q4 ^ ksw) * 8];
            sac[0][ct] = __builtin_amdgcn_mfma_f32_16x16x32_bf16(qw[0][0], kb0, sac[0][ct], 0, 0, 0);
            sac[0][ct] = __builtin_amdgcn_mfma_f32_16x16x32_bf16(qw[0][1], kb1, sac[0][ct], 0, 0, 0);
            sac[1][ct] = __builtin_amdgcn_mfma_f32_16x16x32_bf16(qw[1][0], kb0, sac[1][ct], 0, 0, 0);
            sac[1][ct] = __builtin_amdgcn_mfma_f32_16x16x32_bf16(qw[1][1], kb1, sac[1][ct], 0, 0, 0);
        }
        __builtin_amdgcn_s_setprio(0);

        // ---- per group: bd window MFMAs + band extract + softmax ----
        #pragma unroll
        for (int g = 0; g < 2; g++) {
            const int bg = 112 - w * 32 - g * 16;   // window base offset
            __builtin_amdgcn_s_setprio(1);
            f32x4 bacc[5] = {};
            #pragma unroll
            for (int wc = 0; wc < 5; wc++) {
                const int S = bg + wc * 16;          // 0..176
                const u16* pr_ = &krp[(jt + (S >> 6)) & 3][(S & 63) + l15][0];
                bf16x8 b0 = *(const bf16x8*)(pr_ + sA);
                bf16x8 b1 = *(const bf16x8*)(pr_ + sB);
                bacc[wc] = __builtin_amdgcn_mfma_f32_16x16x32_bf16(qr[g][0], b0, bacc[wc], 0, 0, 0);
                bacc[wc] = __builtin_amdgcn_mfma_f32_16x16x32_bf16(qr[g][1], b1, bacc[wc], 0, 0, 0);
            }
            __builtin_amdgcn_s_setprio(0);

            #pragma unroll
            for (int rg = 0; rg < 4; rg++) {
                const int row = q4 * 4 + rg;                     // group-local
                const ulonglong2 mp = pk_lds[cb][w * 32 + g * 16 + row];
                const unsigned long long mx = mp.x >> l15;
                const unsigned long long sy = mp.y >> l15;
                const int v = l15 + 15 - row;          // in [0,30]
                const int srcl = (q4 << 4) | (v & 15);
                float sh[5];
                #pragma unroll
                for (int w5 = 0; w5 < 5; w5++)
                    sh[w5] = __shfl(bacc[w5][rg], srcl, 64);
                const float e0 = e_rg[0][g][rg];
                const float e1 = e_rg[1][g][rg];
                float s0 = 0.f;
                #pragma unroll
                for (int ct = 0; ct < 4; ct++) {
                    const float bd = (v < 16) ? sh[ct] : sh[ct + 1];
                    const float ef = ((sy >> (ct * 16)) & 1ull) ? e1 : e0;
                    float sarg = sac[g][ct][rg] + bd + ef;
                    sarg = ((mx >> (ct * 16)) & 1ull) ? -1.0e30f : sarg;
                    const float p = __builtin_amdgcn_exp2f(sarg);   // masked -> +0
                    const int pg = (2 * ct + (l15 >> 3)) ^ (row & 7);
                    p_lds[w][g * 16 + row][pg * 8 + (l15 & 7)] = f2bf(p);
                    s0 += p;
                }
                l_r[g][rg] += s0;
            }
        }

        // ---- V(jt) retire (counted: keeps k/pk in flight) + visibility ----
        if (jt == JT - 1) asm volatile("s_waitcnt vmcnt(0)" ::: "memory");
        else              asm volatile("s_waitcnt vmcnt(4)" ::: "memory");
        FBAR();
        // kr panel jt+3 staged here: covered by PV + seam (kr is L2-hot).
        if (jt < JT - 1) STAGE_KR(jt + 3);

        // ---- PV for both groups (v-frags shared) ----
        __builtin_amdgcn_s_setprio(1);
        #pragma unroll
        for (int kk = 0; kk < 2; kk++) {
            bf16x8 vf[4];
            #pragma unroll
            for (int dt = 0; dt < 4; dt++)
                vf[dt] = *(const bf16x8*)&v1[kk][dt * 16 + l15][(q4 ^ ksw) * 8];
            #pragma unroll
            for (int g = 0; g < 2; g++) {
                const int pgr = ((kk * 4 + q4) ^ (l15 & 7)) * 8;
                bf16x8 pf = *(const bf16x8*)&p_lds[w][g * 16 + l15][pgr];
                #pragma unroll
                for (int dt = 0; dt < 4; dt++)
                    o[g][dt] = __builtin_amdgcn_mfma_f32_16x16x32_bf16(pf, vf[dt], o[g][dt], 0, 0, 0);
            }
        }
        __builtin_amdgcn_s_setprio(0);

        // ---- seam ----
        if (jt < JT - 1) {
            FBAR();
            STAGE_V(jt + 1);
            if (jt + 2 < JT) {
                STAGE_K(jt + 2);
                STAGE_PK(jt + 2);
                asm volatile("s_waitcnt vmcnt(6)" ::: "memory");
            } else {
                asm volatile("s_waitcnt vmcnt(2)" ::: "memory");
            }
            FBAR();
        }
    }

    // ---- epilogue: quad-reduce l_r, normalize, write attn_vec ----
    #pragma unroll
    for (int g = 0; g < 2; g++)
        #pragma unroll
        for (int rg = 0; rg < 4; rg++) {
            #pragma unroll
            for (int off = 1; off < 16; off <<= 1)
                l_r[g][rg] += __shfl_xor(l_r[g][rg], off, 64);
            l_r[g][rg] = 1.f / l_r[g][rg];
        }
    #pragma unroll
    for (int g = 0; g < 2; g++)
        #pragma unroll
        for (int dt = 0; dt < 4; dt++)
            #pragma unroll
            for (int rg = 0; rg < 4; rg++) {
                const int row = q4 * 4 + rg;
                const int ii = ib + g * 16 + row;
                const int d = dt * 16 + l15;
                const float v = o[g][dt][rg] * l_r[g][rg];
                av_s[(size_t)(ii * BS + b) * DM + n * DH + d] = f2bf(v);
            }
}

// ---------------------------------------------------------------------------
// Residual + LayerNorm: out = LN(ao + h) * gamma + beta. One block per row.
// ---------------------------------------------------------------------------
__global__ __launch_bounds__(256) void ln_kernel(
    const float* __restrict__ ao, const float* __restrict__ h,
    const float* __restrict__ gamma, const float* __restrict__ beta,
    float* __restrict__ out)
{
    __shared__ float red[8];
    const int row = blockIdx.x, t = threadIdx.x;
    const float* a  = ao + (size_t)row * DM;
    const float* hh = h  + (size_t)row * DM;
    float4 av = *(const float4*)(a + t * 4);
    float4 hv = *(const float4*)(hh + t * 4);
    const float x0 = av.x + hv.x, x1 = av.y + hv.y;
    const float x2 = av.z + hv.z, x3 = av.w + hv.w;
    float s = x0 + x1 + x2 + x3;
    float s2 = x0 * x0 + x1 * x1 + x2 * x2 + x3 * x3;
    #pragma unroll
    for (int off = 1; off < 64; off <<= 1) {
        s  += __shfl_xor(s, off, 64);
        s2 += __shfl_xor(s2, off, 64);
    }
    const int w = t >> 6;
    if ((t & 63) == 0) { red[w] = s; red[4 + w] = s2; }
    __syncthreads();
    s  = red[0] + red[1] + red[2] + red[3];
    s2 = red[4] + red[5] + red[6] + red[7];
    const float mu = s * (1.f / DM);
    const float var = s2 * (1.f / DM) - mu * mu;
    const float rstd = rsqrtf(var + 1e-12f);
    float4 g  = *(const float4*)(gamma + t * 4);
    float4 bb = *(const float4*)(beta + t * 4);
    float4 ov;
    ov.x = (x0 - mu) * rstd * g.x + bb.x;
    ov.y = (x1 - mu) * rstd * g.y + bb.y;
    ov.z = (x2 - mu) * rstd * g.z + bb.z;
    ov.w = (x3 - mu) * rstd * g.w + bb.w;
    *(float4*)(out + (size_t)row * DM + t * 4) = ov;
}

// ---------------------------------------------------------------------------
extern "C" void kernel_launch(void* const* d_in, const int* in_sizes, int n_in,
                              void* d_out, int out_size, void* d_ws, size_t ws_size,
                              hipStream_t stream) {
    (void)in_sizes; (void)n_in; (void)out_size; (void)ws_size;
    const float* h    = (const float*)d_in[0];
    const float* r    = (const float*)d_in[1];
    const float* mems = (const float*)d_in[2];
    const float* mask = (const float*)d_in[3];
    const float* segm = (const float*)d_in[4];
    const float* Wq   = (const float*)d_in[5];
    const float* Wk   = (const float*)d_in[6];
    const float* Wv   = (const float*)d_in[7];
    const float* Wo   = (const float*)d_in[8];
    const float* Wr   = (const float*)d_in[9];
    const float* rwb  = (const float*)d_in[10];
    const float* rrb  = (const float*)d_in[11];
    const float* rsb  = (const float*)d_in[12];
    const float* semb = (const float*)d_in[13];
    const float* gam  = (const float*)d_in[14];
    const float* bet  = (const float*)d_in[15];
    float* out = (float*)d_out;

    char* wsb = (char*)d_ws;
    size_t off = 0;
    auto alloc = [&](size_t bytes) -> void* {
        void* p = wsb + off; off += (bytes + 255) & ~(size_t)255; return p;
    };
    u16* catb = (u16*)alloc((size_t)KL * BS * DM * 2);
    u16* rb   = (u16*)alloc((size_t)RL * BS * DM * 2);
    u16* WqT  = (u16*)alloc((size_t)DM * DM * 2);
    u16* WkT  = (u16*)alloc((size_t)DM * DM * 2);
    u16* WvT  = (u16*)alloc((size_t)DM * DM * 2);
    u16* WrT  = (u16*)alloc((size_t)DM * DM * 2);
    u16* WoB  = (u16*)alloc((size_t)DM * DM * 2);
    float* q_s = (float*)alloc((size_t)BS * NH * QL * DH * 4);
    u16* k_s  = (u16*)alloc((size_t)BS * NH * KL * DH * 2);
    u16* vt_s = (u16*)alloc((size_t)BS * NH * KL * DH * 2);
    u16* kr_s = (u16*)alloc((size_t)BS * NH * RL * DH * 2 + 8192); // tail pad: kr window over-read
    u16* av_s = (u16*)alloc((size_t)QL * BS * DM * 2);
    float* ao_s = (float*)alloc((size_t)QL * BS * DM * 4);
    ulonglong2* pk = (ulonglong2*)alloc((size_t)BS * QL * JT * 16);
    u16* v_s = (u16*)ao_s;   // alias: v_s dead before ao_s is written

    // 1) fused prep: convert + W transpose + mask/seg pack (one launch)
    prep_kernel<<<43008, 256, 0, stream>>>(mems, h, r, Wo, mask, segm,
                                           Wq, Wk, Wv, Wr,
                                           catb, rb, WoB,
                                           WqT, WkT, WvT, WrT, pk);
    // 2) all 4 projections in one launch (hb = h part of catb)
    const u16* hb = catb + (size_t)2048 * DM;
    proj_kernel<<<1664, 256, 0, stream>>>(hb, catb, rb, WqT, WkT, WvT, WrT,
                                          q_s, k_s, v_s, kr_s);
    // 2b) v -> v^T
    vtrans_kernel<<<dim3(JT, 64), 256, 0, stream>>>(v_s, vt_s);
    // 3) fused attention — grid (bn, itile128): XCD = bn%8 locality swizzle
    attn_kernel<<<dim3(64, 8), 256, 0, stream>>>(q_s, k_s, vt_s, kr_s, pk,
                                                 rwb, rrb, rsb, semb, av_s);
    // 4) output projection + residual layernorm
    ogemm_kernel<<<dim3(32, 8), 256, 0, stream>>>(av_s, WoB, ao_s);
    ln_kernel<<<4096, 256, 0, stream>>>(ao_s, h, gam, bet, out);
}